// Round 3
// baseline (189.762 us; speedup 1.0000x reference)
//
#include <hip/hip_runtime.h>
#include <hip/hip_bf16.h>
#include <math.h>

// AutoCorrelation (Autoformer). B=16, L=2048, H=8, E=64, fp32.
// Round 3: pack with float4 both sides + transposed-LDS (b128 reads);
// fft with 4 channels/block + register prefetch + iterative twiddles;
// partial reduction staged into free z rows, folded into ifft.

#define B_ 16
#define L_ 2048
#define H_ 8
#define E_ 64
#define C_ (H_ * E_)      // 512 channels per batch
#define NCH (B_ * C_)     // 8192
#define K_ 7
#define CPB 4             // channels per fft block

// ---------- workspace layout (identical footprint to round 2) ----------
#define Z_OFF   0ull                               // float2[NCH][L] = 128 MiB (reused for partials + R)
#define S_OFF   134217728ull                       // (unused this round)
#define MV_OFF  (S_OFF + 262144ull)                // float [B][L]
#define TK_OFF  (MV_OFF + 131072ull)               // int[7]
#define W_OFF   (TK_OFF + 64ull)                   // float[16][7]

// ---------- complex helpers ----------
__device__ __forceinline__ float2 cadd(float2 a, float2 b) { return make_float2(a.x + b.x, a.y + b.y); }
__device__ __forceinline__ float2 csub(float2 a, float2 b) { return make_float2(a.x - b.x, a.y - b.y); }
__device__ __forceinline__ float2 cmul(float2 a, float2 b) {
  return make_float2(fmaf(a.x, b.x, -a.y * b.y), fmaf(a.x, b.y, a.y * b.x));
}
__device__ __forceinline__ float2 cis(float ang) { float s, c; sincosf(ang, &s, &c); return make_float2(c, s); }

template<int S> __device__ __forceinline__ float2 rot90(float2 z) {  // *W_4^{S}: S=-1 -> -i*z
  return (S < 0) ? make_float2(z.y, -z.x) : make_float2(-z.y, z.x);
}
template<int S> __device__ __forceinline__ void dft4(float2& a, float2& b, float2& c, float2& d) {
  float2 t0 = cadd(a, c), t1 = csub(a, c), t2 = cadd(b, d), t3 = rot90<S>(csub(b, d));
  a = cadd(t0, t2); c = csub(t0, t2); b = cadd(t1, t3); d = csub(t1, t3);
}
template<int S> __device__ __forceinline__ void dft8(float2 v[8]) {
  const float RT = 0.70710678118654752f;
  const float SR = (S < 0) ? -RT : RT;
  float2 a0 = cadd(v[0], v[4]), a1 = cadd(v[1], v[5]), a2 = cadd(v[2], v[6]), a3 = cadd(v[3], v[7]);
  float2 b0 = csub(v[0], v[4]), b1 = csub(v[1], v[5]), b2 = csub(v[2], v[6]), b3 = csub(v[3], v[7]);
  b1 = cmul(b1, make_float2(RT, SR));     // W8^{S}
  b2 = rot90<S>(b2);                      // W8^{2S}
  b3 = cmul(b3, make_float2(-RT, SR));    // W8^{3S}
  dft4<S>(a0, a1, a2, a3);
  dft4<S>(b0, b1, b2, b3);
  v[0] = a0; v[2] = a1; v[4] = a2; v[6] = a3;
  v[1] = b0; v[3] = b1; v[5] = b2; v[7] = b3;
}
// padded LDS index for fft buf: +1 element per 32
__device__ __forceinline__ int sg(int e) { return e + (e >> 5); }

// ---------- kernel T: pack q,k -> z[ch][t], float4 loads + float4 stores ----------
// LDS stored transposed [channel-e][t] so phase-2 reads are contiguous b128.
// t-chunk XOR swizzle by (e>>2)&3 keeps phase-1 column writes at <=4-way.
__global__ __launch_bounds__(256) void pack_transpose_kernel(
    const float* __restrict__ q, const float* __restrict__ k,
    float2* __restrict__ z) {
  __shared__ float2 tileT[64][66];   // [e][t], row stride 66 float2 (132 words, 16B-aligned rows)
  int bi = blockIdx.x;
  int tt = bi & 31; bi >>= 5;       // t-tile (L/64)
  int h  = bi & 7;  bi >>= 3;
  int b  = bi;
  int t0 = tt * 64;
  int tid = threadIdx.x;

  // phase 1: coalesced float4 reads of q,k; scatter into tileT columns
  int e4 = tid & 15;                // float4 block along e: er = 4*e4
  int tr = tid >> 4;                // 0..15
  int cmask = (e4 & 3) << 2;        // xor on t bits 2..3 (row>>2 == e4 for rows 4e4..4e4+3)
#pragma unroll
  for (int p = 0; p < 4; ++p) {
    int t = tr + 16 * p;
    size_t idx = ((size_t)(b * L_ + t0 + t) * H_ + h) * E_ + 4 * e4;
    float4 qv = *(const float4*)(q + idx);
    float4 kv = *(const float4*)(k + idx);
    int tc = t ^ cmask;
    tileT[4 * e4 + 0][tc] = make_float2(qv.x, kv.x);
    tileT[4 * e4 + 1][tc] = make_float2(qv.y, kv.y);
    tileT[4 * e4 + 2][tc] = make_float2(qv.z, kv.z);
    tileT[4 * e4 + 3][tc] = make_float2(qv.w, kv.w);
  }
  __syncthreads();

  // phase 2: contiguous b128 LDS reads, coalesced float4 global writes
  int e = tid >> 2;                 // channel 0..63
  int s = tid & 3;                  // t-quarter
  int rmask = ((e >> 2) & 3) << 1;  // chunk-index form of the xor (bits 1..2 of float4 idx)
  const float4* src = (const float4*)&tileT[e][0];
  size_t zrow = ((size_t)((b * H_ + h) * E_ + e)) * L_ + t0;
  float4* zp = (float4*)(z + zrow);
#pragma unroll
  for (int c = 0; c < 8; ++c) {
    zp[8 * s + c] = src[(8 * s + c) ^ rmask];
  }
}

// ---------- kernel F: radix-8/8/8/4 DIF FFT + freq product, CPB channels/block ----------
// Digit-reversed storage p = 256k1+32k2+4k3+k4, frequency f(p) = k1+8k2+64k3+512k4.
__global__ __launch_bounds__(256) void fft_corr_kernel(float2* __restrict__ z) {
  __shared__ float2 buf[2112];
  int t = threadIdx.x;
  int j2 = t & 31, j3 = t & 3;
  float2 tw1[7], tw2[7], tw3[7];
  {
    float2 w1 = cis(-6.283185307179586f * (float)t  / 2048.0f);
    float2 w2 = cis(-6.283185307179586f * (float)j2 / 256.0f);
    float2 w3 = cis(-6.283185307179586f * (float)j3 / 32.0f);
    tw1[0] = w1; tw2[0] = w2; tw3[0] = w3;
#pragma unroll
    for (int k = 1; k < 7; ++k) {
      tw1[k] = cmul(tw1[k - 1], w1);
      tw2[k] = cmul(tw2[k - 1], w2);
      tw3[k] = cmul(tw3[k - 1], w3);
    }
  }
  float2 acc[8];
#pragma unroll
  for (int k = 0; k < 8; ++k) acc[k] = make_float2(0.f, 0.f);
  int cbase = blockIdx.x * CPB;
  int base2 = (t >> 5) * 256 + j2;
  int base3 = (t >> 2) * 32 + j3;

  // prefetch channel 0
  float2 nxt[8];
  {
    const float2* r0 = z + (size_t)cbase * L_;
#pragma unroll
    for (int m = 0; m < 8; ++m) nxt[m] = r0[t + 256 * m];
  }

  for (int c = 0; c < CPB; ++c) {
    float2 v[8];
#pragma unroll
    for (int m = 0; m < 8; ++m) v[m] = nxt[m];
    if (c + 1 < CPB) {               // prefetch next channel under this one's compute
      const float2* rn = z + (size_t)(cbase + c + 1) * L_;
#pragma unroll
      for (int m = 0; m < 8; ++m) nxt[m] = rn[t + 256 * m];
    }
    // stage 1: M=2048
    dft8<-1>(v);
#pragma unroll
    for (int k = 1; k < 8; ++k) v[k] = cmul(v[k], tw1[k - 1]);
    __syncthreads();                 // protect prev product-phase reads
#pragma unroll
    for (int k = 0; k < 8; ++k) buf[sg(t + 256 * k)] = v[k];
    __syncthreads();
    // stage 2: M=256
#pragma unroll
    for (int m = 0; m < 8; ++m) v[m] = buf[sg(base2 + 32 * m)];
    dft8<-1>(v);
#pragma unroll
    for (int k = 1; k < 8; ++k) v[k] = cmul(v[k], tw2[k - 1]);
    __syncthreads();
#pragma unroll
    for (int k = 0; k < 8; ++k) buf[sg(base2 + 32 * k)] = v[k];
    __syncthreads();
    // stage 3: M=32
#pragma unroll
    for (int m = 0; m < 8; ++m) v[m] = buf[sg(base3 + 4 * m)];
    dft8<-1>(v);
#pragma unroll
    for (int k = 1; k < 8; ++k) v[k] = cmul(v[k], tw3[k - 1]);
    __syncthreads();
#pragma unroll
    for (int k = 0; k < 8; ++k) buf[sg(base3 + 4 * k)] = v[k];
    __syncthreads();
    // stage 4: M=4 radix-4, thread-private
    float2 u[8];
#pragma unroll
    for (int k = 0; k < 8; ++k) u[k] = buf[sg(8 * t + k)];
    dft4<-1>(u[0], u[1], u[2], u[3]);
    dft4<-1>(u[4], u[5], u[6], u[7]);
#pragma unroll
    for (int k = 0; k < 8; ++k) buf[sg(8 * t + k)] = u[k];
    __syncthreads();
    // product: P = Qf*conj(Kf) via two-real trick; -f located by digit arithmetic
#pragma unroll
    for (int k = 0; k < 8; ++k) {
      int p = 8 * t + k;
      int f = ((p >> 8) & 7) | (((p >> 5) & 7) << 3) | (((p >> 2) & 7) << 6) | ((p & 3) << 9);
      int fp = (2048 - f) & 2047;
      int pp = ((fp & 7) << 8) | (((fp >> 3) & 7) << 5) | (((fp >> 6) & 7) << 2) | ((fp >> 9) & 3);
      float2 A = u[k];
      float2 Bc = buf[sg(pp)];
      acc[k].x += 0.5f  * (Bc.x * A.y + Bc.y * A.x);
      acc[k].y += 0.25f * (A.x * A.x + A.y * A.y - Bc.x * Bc.x - Bc.y * Bc.y);
    }
  }
  // transpose acc through LDS so the partial write is coalesced; reuse own z slice row 0
  __syncthreads();
#pragma unroll
  for (int k = 0; k < 8; ++k) buf[sg(8 * t + k)] = acc[k];
  __syncthreads();
  float2* part = z + (size_t)cbase * L_;
#pragma unroll
  for (int m = 0; m < 8; ++m) part[t + 256 * m] = buf[sg(t + 256 * m)];
}

// ---------- kernel R: stage-A reduce: 128 partials/batch -> 8 groups/batch ----------
// Group sums are stored in FREE rows of z (row (b*128+g*16)*CPB + 1), so no new ws.
__global__ __launch_bounds__(256) void reduce_R_kernel(float2* __restrict__ z) {
  int idx = blockIdx.x * 256 + threadIdx.x;   // 0..262143
  int p = idx & 2047;
  int g = (idx >> 11) & 7;
  int b = idx >> 14;
  float2 s = make_float2(0.f, 0.f);
#pragma unroll 4
  for (int i = 0; i < 16; ++i) {
    int part = b * 128 + g * 16 + i;
    float2 vv = z[(size_t)(part * CPB) * L_ + p];
    s.x += vv.x; s.y += vv.y;
  }
  z[(size_t)((b * 128 + g * 16) * CPB + 1) * L_ + p] = s;
}

// ---------- kernel I: sum 8 group-partials + mirrored DIT inverse ----------
__global__ __launch_bounds__(256) void ifft_kernel(
    const float2* __restrict__ z, float* __restrict__ mv) {
  __shared__ float2 buf[2112];
  int t = threadIdx.x, b = blockIdx.x;
  int j2 = t & 31, j3 = t & 3;
  float2 tw1[7], tw2[7], tw3[7];
  {
    float2 w1 = cis(6.283185307179586f * (float)t  / 2048.0f);
    float2 w2 = cis(6.283185307179586f * (float)j2 / 256.0f);
    float2 w3 = cis(6.283185307179586f * (float)j3 / 32.0f);
    tw1[0] = w1; tw2[0] = w2; tw3[0] = w3;
#pragma unroll
    for (int k = 1; k < 7; ++k) {
      tw1[k] = cmul(tw1[k - 1], w1);
      tw2[k] = cmul(tw2[k - 1], w2);
      tw3[k] = cmul(tw3[k - 1], w3);
    }
  }
  int base2 = (t >> 5) * 256 + j2;
  int base3 = (t >> 2) * 32 + j3;
  // stage A: final 8-way reduction + M=4 DFT (no twiddle), quads 8t..8t+7
  float2 u[8];
#pragma unroll
  for (int k = 0; k < 8; ++k) u[k] = make_float2(0.f, 0.f);
#pragma unroll
  for (int g = 0; g < 8; ++g) {
    const float4* rp = (const float4*)(z + (size_t)((b * 128 + g * 16) * CPB + 1) * L_);
#pragma unroll
    for (int m = 0; m < 4; ++m) {
      float4 f = rp[4 * t + m];
      u[2 * m].x     += f.x; u[2 * m].y     += f.y;
      u[2 * m + 1].x += f.z; u[2 * m + 1].y += f.w;
    }
  }
  dft4<1>(u[0], u[1], u[2], u[3]);
  dft4<1>(u[4], u[5], u[6], u[7]);
#pragma unroll
  for (int k = 0; k < 8; ++k) buf[sg(8 * t + k)] = u[k];
  __syncthreads();
  // stage B: M=32 (twiddle inputs, then inverse DFT)
  float2 v[8];
#pragma unroll
  for (int k = 0; k < 8; ++k) v[k] = buf[sg(base3 + 4 * k)];
#pragma unroll
  for (int k = 1; k < 8; ++k) v[k] = cmul(v[k], tw3[k - 1]);
  dft8<1>(v);
  __syncthreads();
#pragma unroll
  for (int m = 0; m < 8; ++m) buf[sg(base3 + 4 * m)] = v[m];
  __syncthreads();
  // stage C: M=256
#pragma unroll
  for (int k = 0; k < 8; ++k) v[k] = buf[sg(base2 + 32 * k)];
#pragma unroll
  for (int k = 1; k < 8; ++k) v[k] = cmul(v[k], tw2[k - 1]);
  dft8<1>(v);
  __syncthreads();
#pragma unroll
  for (int m = 0; m < 8; ++m) buf[sg(base2 + 32 * m)] = v[m];
  __syncthreads();
  // stage D: M=2048 -> natural-order x[t+256m]
#pragma unroll
  for (int k = 0; k < 8; ++k) v[k] = buf[sg(t + 256 * k)];
#pragma unroll
  for (int k = 1; k < 8; ++k) v[k] = cmul(v[k], tw1[k - 1]);
  dft8<1>(v);
  const float scale = 1.0f / (2048.0f * 512.0f);  // 1/N * mean over H*E
#pragma unroll
  for (int m = 0; m < 8; ++m) mv[b * L_ + t + 256 * m] = v[m].x * scale;
}

// ---------- kernel K: batch-mean top-7 + per-batch softmax weights ----------
__global__ __launch_bounds__(256) void topk_kernel(
    const float* __restrict__ mv, int* __restrict__ topk, float* __restrict__ wts) {
  __shared__ float av[2048];
  __shared__ float rv[256];
  __shared__ int   ri[256];
  __shared__ int   sidx[K_];
  int tid = threadIdx.x;
  for (int d = tid; d < 2048; d += 256) {
    float s = 0.f;
#pragma unroll
    for (int b = 0; b < B_; ++b) s += mv[b * L_ + d];
    av[d] = s;
  }
  __syncthreads();
  for (int k = 0; k < K_; ++k) {
    float bv = -INFINITY; int bi = 0;
    for (int d = tid; d < 2048; d += 256) {
      float vv = av[d];
      if (vv > bv) { bv = vv; bi = d; }
    }
    rv[tid] = bv; ri[tid] = bi;
    __syncthreads();
    for (int off = 128; off > 0; off >>= 1) {
      if (tid < off) {
        float v2 = rv[tid + off]; int i2 = ri[tid + off];
        if (v2 > rv[tid] || (v2 == rv[tid] && i2 < ri[tid])) { rv[tid] = v2; ri[tid] = i2; }
      }
      __syncthreads();
    }
    if (tid == 0) { sidx[k] = ri[0]; av[ri[0]] = -INFINITY; }
    __syncthreads();
  }
  if (tid < K_) topk[tid] = sidx[tid];
  if (tid < B_) {
    float x[K_], m = -INFINITY;
#pragma unroll
    for (int k = 0; k < K_; ++k) { x[k] = mv[tid * L_ + sidx[k]]; m = fmaxf(m, x[k]); }
    float s = 0.f;
#pragma unroll
    for (int k = 0; k < K_; ++k) { x[k] = expf(x[k] - m); s += x[k]; }
#pragma unroll
    for (int k = 0; k < K_; ++k) wts[tid * K_ + k] = x[k] / s;
  }
}

// ---------- kernel G: out[b,t,h,e] = sum_k w[b,k] * v[b,(t+d_k)%L,h,e] ----------
__global__ __launch_bounds__(256) void aggregate_kernel(
    const float4* __restrict__ v4, const int* __restrict__ topk,
    const float* __restrict__ wts, float4* __restrict__ out4) {
  __shared__ int   sidx[K_];
  __shared__ float sw[B_][K_];
  int tid = threadIdx.x;
  if (tid < K_) sidx[tid] = topk[tid];
  if (tid < B_ * K_) sw[tid / K_][tid % K_] = wts[tid];
  __syncthreads();
  int idx = blockIdx.x * 256 + tid;
  int c4  = idx & 127;
  int row = idx >> 7;
  int t   = row & (L_ - 1);
  int b   = row >> 11;
  float4 acc = make_float4(0.f, 0.f, 0.f, 0.f);
#pragma unroll
  for (int k = 0; k < K_; ++k) {
    int s = t + sidx[k];
    if (s >= L_) s -= L_;
    float w = sw[b][k];
    float4 val = v4[((size_t)(b * L_ + s) << 7) + c4];
    acc.x += w * val.x; acc.y += w * val.y;
    acc.z += w * val.z; acc.w += w * val.w;
  }
  out4[idx] = acc;
}

extern "C" void kernel_launch(void* const* d_in, const int* in_sizes, int n_in,
                              void* d_out, int out_size, void* d_ws, size_t ws_size,
                              hipStream_t stream) {
  const float* q = (const float*)d_in[0];
  const float* k = (const float*)d_in[1];
  const float* v = (const float*)d_in[2];
  float* out = (float*)d_out;

  char* ws = (char*)d_ws;
  float2* z    = (float2*)(ws + Z_OFF);
  float*  mv   = (float*) (ws + MV_OFF);
  int*    topk = (int*)   (ws + TK_OFF);
  float*  wts  = (float*) (ws + W_OFF);

  pack_transpose_kernel<<<B_ * H_ * (L_ / 64), 256, 0, stream>>>(q, k, z);
  fft_corr_kernel<<<NCH / CPB, 256, 0, stream>>>(z);
  reduce_R_kernel<<<(B_ * 8 * L_) / 256, 256, 0, stream>>>(z);
  ifft_kernel<<<B_, 256, 0, stream>>>(z, mv);
  topk_kernel<<<1, 256, 0, stream>>>(mv, topk, wts);
  aggregate_kernel<<<(B_ * L_ * C_ / 4) / 256, 256, 0, stream>>>(
      (const float4*)v, topk, wts, (float4*)out);
}

// Round 4
// 156.911 us; speedup vs baseline: 1.2094x; 1.2094x over previous
//
#include <hip/hip_runtime.h>
#include <hip/hip_bf16.h>
#include <math.h>

// AutoCorrelation (Autoformer). B=16, L=2048, H=8, E=64, fp32.
// Round 4: pack/z eliminated. fft_corr reads q,k DIRECTLY in [b,t,h,e] layout
// (float4 along e = 4 channels/block); L3 (256MB) retains the 134MB input so
// the 4x cacheline amplification never hits HBM; XCD swizzle co-locates the
// 4 line-sharing blocks on one L2. Stage math / product / reduce / ifft /
// topk / aggregate identical to the verified round-3 kernel. Mid-stage
// barriers removed (stages 2-4 are thread-private permutations).

#define B_ 16
#define L_ 2048
#define H_ 8
#define E_ 64
#define C_ (H_ * E_)      // 512 channels per batch
#define NCH (B_ * C_)     // 8192
#define K_ 7

// ---------- workspace layout ----------
#define PART_OFF 0ull                              // float2[2048][2048] = 32 MiB
#define SG_OFF   33554432ull                       // float2[16][8][2048] = 2 MiB
#define MV_OFF   (SG_OFF + 2097152ull)             // float [B][L]
#define TK_OFF   (MV_OFF + 131072ull)              // int[7]
#define W_OFF    (TK_OFF + 64ull)                  // float[16][7]

// ---------- complex helpers ----------
__device__ __forceinline__ float2 cadd(float2 a, float2 b) { return make_float2(a.x + b.x, a.y + b.y); }
__device__ __forceinline__ float2 csub(float2 a, float2 b) { return make_float2(a.x - b.x, a.y - b.y); }
__device__ __forceinline__ float2 cmul(float2 a, float2 b) {
  return make_float2(fmaf(a.x, b.x, -a.y * b.y), fmaf(a.x, b.y, a.y * b.x));
}
__device__ __forceinline__ float2 cis(float ang) { float s, c; sincosf(ang, &s, &c); return make_float2(c, s); }

template<int S> __device__ __forceinline__ float2 rot90(float2 z) {  // *W_4^{S}: S=-1 -> -i*z
  return (S < 0) ? make_float2(z.y, -z.x) : make_float2(-z.y, z.x);
}
template<int S> __device__ __forceinline__ void dft4(float2& a, float2& b, float2& c, float2& d) {
  float2 t0 = cadd(a, c), t1 = csub(a, c), t2 = cadd(b, d), t3 = rot90<S>(csub(b, d));
  a = cadd(t0, t2); c = csub(t0, t2); b = cadd(t1, t3); d = csub(t1, t3);
}
template<int S> __device__ __forceinline__ void dft8(float2 v[8]) {
  const float RT = 0.70710678118654752f;
  const float SR = (S < 0) ? -RT : RT;
  float2 a0 = cadd(v[0], v[4]), a1 = cadd(v[1], v[5]), a2 = cadd(v[2], v[6]), a3 = cadd(v[3], v[7]);
  float2 b0 = csub(v[0], v[4]), b1 = csub(v[1], v[5]), b2 = csub(v[2], v[6]), b3 = csub(v[3], v[7]);
  b1 = cmul(b1, make_float2(RT, SR));     // W8^{S}
  b2 = rot90<S>(b2);                      // W8^{2S}
  b3 = cmul(b3, make_float2(-RT, SR));    // W8^{3S}
  dft4<S>(a0, a1, a2, a3);
  dft4<S>(b0, b1, b2, b3);
  v[0] = a0; v[2] = a1; v[4] = a2; v[6] = a3;
  v[1] = b0; v[3] = b1; v[5] = b2; v[7] = b3;
}
// padded LDS index: +1 element per 32
__device__ __forceinline__ int sg(int e) { return e + (e >> 5); }

// ---------- kernel F: fused load + radix-8/8/8/4 DIF FFT + freq product ----------
// 4 channels/block (one float4 along e). Digit-reversed storage
// p = 256k1+32k2+4k3+k4, frequency f(p) = k1+8k2+64k3+512k4.
__global__ __launch_bounds__(256) void fft_corr_kernel(
    const float* __restrict__ q, const float* __restrict__ k,
    float2* __restrict__ part) {
  extern __shared__ float2 dbuf[];        // 4 regions x 2112 float2 = 67584 B
  int t = threadIdx.x;
  int j2 = t & 31, j3 = t & 3;
  float2 tw1[7], tw2[7], tw3[7];
  {
    float2 w1 = cis(-6.283185307179586f * (float)t  / 2048.0f);
    float2 w2 = cis(-6.283185307179586f * (float)j2 / 256.0f);
    float2 w3 = cis(-6.283185307179586f * (float)j3 / 32.0f);
    tw1[0] = w1; tw2[0] = w2; tw3[0] = w3;
#pragma unroll
    for (int kk = 1; kk < 7; ++kk) {
      tw1[kk] = cmul(tw1[kk - 1], w1);
      tw2[kk] = cmul(tw2[kk - 1], w2);
      tw3[kk] = cmul(tw3[kk - 1], w3);
    }
  }
  // XCD swizzle: physical p -> logical l, bijective on [0,2048), such that the
  // 4 logical blocks of each quad (sharing 64B q/k lines) get the same p&7
  // (same XCD under round-robin dispatch) and are dispatched 8 apart.
  int pphys = blockIdx.x;
  int i = pphys >> 3, x = pphys & 7;
  int l = ((i >> 2) << 5) | (x << 2) | (i & 3);
  int cbase = l * 4;
  int b = cbase >> 9, h = (cbase >> 6) & 7, e0 = cbase & 63;
  size_t base = (size_t)b * (L_ * H_ * E_) + (size_t)h * E_ + e0;

  // load all 8 taps x (q,k) as float4 (4 channels each) -- 16 loads in flight
  float4 qv[8], kv[8];
#pragma unroll
  for (int m = 0; m < 8; ++m) {
    size_t a = base + (size_t)(t + 256 * m) * (H_ * E_);
    qv[m] = *(const float4*)(q + a);
    kv[m] = *(const float4*)(k + a);
  }

  float2 acc[8];
#pragma unroll
  for (int kk = 0; kk < 8; ++kk) acc[kk] = make_float2(0.f, 0.f);

  // stage 1 for all 4 channels (regs -> LDS regions)
#pragma unroll
  for (int c = 0; c < 4; ++c) {
    float2 v[8];
#pragma unroll
    for (int m = 0; m < 8; ++m)
      v[m] = make_float2(((const float*)&qv[m])[c], ((const float*)&kv[m])[c]);
    dft8<-1>(v);
#pragma unroll
    for (int kk = 1; kk < 8; ++kk) v[kk] = cmul(v[kk], tw1[kk - 1]);
    float2* bufc = dbuf + c * 2112;
#pragma unroll
    for (int kk = 0; kk < 8; ++kk) bufc[sg(t + 256 * kk)] = v[kk];
  }
  __syncthreads();

  int base2 = (t >> 5) * 256 + j2;
  int base3 = (t >> 2) * 32 + j3;
#pragma unroll
  for (int cp = 0; cp < 2; ++cp) {
    float2* A  = dbuf + (2 * cp) * 2112;
    float2* Bf = dbuf + (2 * cp + 1) * 2112;
    float2 va[8], vb[8];
    // stage 2 (read set == write set per thread: no mid-stage barrier)
#pragma unroll
    for (int m = 0; m < 8; ++m) { va[m] = A[sg(base2 + 32 * m)]; vb[m] = Bf[sg(base2 + 32 * m)]; }
    dft8<-1>(va); dft8<-1>(vb);
#pragma unroll
    for (int kk = 1; kk < 8; ++kk) { va[kk] = cmul(va[kk], tw2[kk - 1]); vb[kk] = cmul(vb[kk], tw2[kk - 1]); }
#pragma unroll
    for (int kk = 0; kk < 8; ++kk) { A[sg(base2 + 32 * kk)] = va[kk]; Bf[sg(base2 + 32 * kk)] = vb[kk]; }
    __syncthreads();
    // stage 3
#pragma unroll
    for (int m = 0; m < 8; ++m) { va[m] = A[sg(base3 + 4 * m)]; vb[m] = Bf[sg(base3 + 4 * m)]; }
    dft8<-1>(va); dft8<-1>(vb);
#pragma unroll
    for (int kk = 1; kk < 8; ++kk) { va[kk] = cmul(va[kk], tw3[kk - 1]); vb[kk] = cmul(vb[kk], tw3[kk - 1]); }
#pragma unroll
    for (int kk = 0; kk < 8; ++kk) { A[sg(base3 + 4 * kk)] = va[kk]; Bf[sg(base3 + 4 * kk)] = vb[kk]; }
    __syncthreads();
    // stage 4 (thread-private quads 8t..8t+7)
#pragma unroll
    for (int kk = 0; kk < 8; ++kk) { va[kk] = A[sg(8 * t + kk)]; vb[kk] = Bf[sg(8 * t + kk)]; }
    dft4<-1>(va[0], va[1], va[2], va[3]); dft4<-1>(va[4], va[5], va[6], va[7]);
    dft4<-1>(vb[0], vb[1], vb[2], vb[3]); dft4<-1>(vb[4], vb[5], vb[6], vb[7]);
#pragma unroll
    for (int kk = 0; kk < 8; ++kk) { A[sg(8 * t + kk)] = va[kk]; Bf[sg(8 * t + kk)] = vb[kk]; }
    __syncthreads();
    // product: P = Qf*conj(Kf) via two-real trick; -f located by digit math
#pragma unroll
    for (int kk = 0; kk < 8; ++kk) {
      int pos = 8 * t + kk;
      int f  = ((pos >> 8) & 7) | (((pos >> 5) & 7) << 3) | (((pos >> 2) & 7) << 6) | ((pos & 3) << 9);
      int fp = (2048 - f) & 2047;
      int pp = ((fp & 7) << 8) | (((fp >> 3) & 7) << 5) | (((fp >> 6) & 7) << 2) | ((fp >> 9) & 3);
      float2 Ax = va[kk], Bc = A[sg(pp)];
      acc[kk].x += 0.5f  * (Bc.x * Ax.y + Bc.y * Ax.x);
      acc[kk].y += 0.25f * (Ax.x * Ax.x + Ax.y * Ax.y - Bc.x * Bc.x - Bc.y * Bc.y);
      Ax = vb[kk]; Bc = Bf[sg(pp)];
      acc[kk].x += 0.5f  * (Bc.x * Ax.y + Bc.y * Ax.x);
      acc[kk].y += 0.25f * (Ax.x * Ax.x + Ax.y * Ax.y - Bc.x * Bc.x - Bc.y * Bc.y);
    }
  }
  // coalesce partial write via LDS transpose (region 0 is dead now)
#pragma unroll
  for (int kk = 0; kk < 8; ++kk) dbuf[sg(8 * t + kk)] = acc[kk];
  __syncthreads();
  float2* prow = part + (size_t)l * L_;   // row index = LOGICAL block id
#pragma unroll
  for (int m = 0; m < 8; ++m) prow[t + 256 * m] = dbuf[sg(t + 256 * m)];
}

// ---------- kernel R: sum 16 partial rows -> Sg[b][g][p] ----------
__global__ __launch_bounds__(256) void reduce_R_kernel(
    const float2* __restrict__ part, float2* __restrict__ Sg) {
  int idx = blockIdx.x * 256 + threadIdx.x;   // 0..262143 = [b][g][p]
  int p = idx & 2047;
  int g = (idx >> 11) & 7;
  int b = idx >> 14;
  float2 s = make_float2(0.f, 0.f);
#pragma unroll 4
  for (int i = 0; i < 16; ++i) {
    float2 vv = part[(size_t)(b * 128 + g * 16 + i) * L_ + p];
    s.x += vv.x; s.y += vv.y;
  }
  Sg[idx] = s;
}

// ---------- kernel I: sum 8 group-partials + mirrored DIT inverse ----------
__global__ __launch_bounds__(256) void ifft_kernel(
    const float2* __restrict__ Sg, float* __restrict__ mv) {
  __shared__ float2 buf[2112];
  int t = threadIdx.x, b = blockIdx.x;
  int j2 = t & 31, j3 = t & 3;
  float2 tw1[7], tw2[7], tw3[7];
  {
    float2 w1 = cis(6.283185307179586f * (float)t  / 2048.0f);
    float2 w2 = cis(6.283185307179586f * (float)j2 / 256.0f);
    float2 w3 = cis(6.283185307179586f * (float)j3 / 32.0f);
    tw1[0] = w1; tw2[0] = w2; tw3[0] = w3;
#pragma unroll
    for (int kk = 1; kk < 7; ++kk) {
      tw1[kk] = cmul(tw1[kk - 1], w1);
      tw2[kk] = cmul(tw2[kk - 1], w2);
      tw3[kk] = cmul(tw3[kk - 1], w3);
    }
  }
  int base2 = (t >> 5) * 256 + j2;
  int base3 = (t >> 2) * 32 + j3;
  // stage A: final 8-way reduction + M=4 DFT (no twiddle), quads 8t..8t+7
  float2 u[8];
#pragma unroll
  for (int kk = 0; kk < 8; ++kk) u[kk] = make_float2(0.f, 0.f);
#pragma unroll
  for (int g = 0; g < 8; ++g) {
    const float4* rp = (const float4*)(Sg + (size_t)(b * 8 + g) * L_);
#pragma unroll
    for (int m = 0; m < 4; ++m) {
      float4 f = rp[4 * t + m];
      u[2 * m].x     += f.x; u[2 * m].y     += f.y;
      u[2 * m + 1].x += f.z; u[2 * m + 1].y += f.w;
    }
  }
  dft4<1>(u[0], u[1], u[2], u[3]);
  dft4<1>(u[4], u[5], u[6], u[7]);
#pragma unroll
  for (int kk = 0; kk < 8; ++kk) buf[sg(8 * t + kk)] = u[kk];
  __syncthreads();
  // stage B: M=32 (twiddle inputs, then inverse DFT)
  float2 v[8];
#pragma unroll
  for (int kk = 0; kk < 8; ++kk) v[kk] = buf[sg(base3 + 4 * kk)];
#pragma unroll
  for (int kk = 1; kk < 8; ++kk) v[kk] = cmul(v[kk], tw3[kk - 1]);
  dft8<1>(v);
  __syncthreads();
#pragma unroll
  for (int m = 0; m < 8; ++m) buf[sg(base3 + 4 * m)] = v[m];
  __syncthreads();
  // stage C: M=256
#pragma unroll
  for (int kk = 0; kk < 8; ++kk) v[kk] = buf[sg(base2 + 32 * kk)];
#pragma unroll
  for (int kk = 1; kk < 8; ++kk) v[kk] = cmul(v[kk], tw2[kk - 1]);
  dft8<1>(v);
  __syncthreads();
#pragma unroll
  for (int m = 0; m < 8; ++m) buf[sg(base2 + 32 * m)] = v[m];
  __syncthreads();
  // stage D: M=2048 -> natural-order x[t+256m]
#pragma unroll
  for (int kk = 0; kk < 8; ++kk) v[kk] = buf[sg(t + 256 * kk)];
#pragma unroll
  for (int kk = 1; kk < 8; ++kk) v[kk] = cmul(v[kk], tw1[kk - 1]);
  dft8<1>(v);
  const float scale = 1.0f / (2048.0f * 512.0f);  // 1/N * mean over H*E
#pragma unroll
  for (int m = 0; m < 8; ++m) mv[b * L_ + t + 256 * m] = v[m].x * scale;
}

// ---------- kernel K: batch-mean top-7 + per-batch softmax weights ----------
__global__ __launch_bounds__(256) void topk_kernel(
    const float* __restrict__ mv, int* __restrict__ topk, float* __restrict__ wts) {
  __shared__ float av[2048];
  __shared__ float rv[256];
  __shared__ int   ri[256];
  __shared__ int   sidx[K_];
  int tid = threadIdx.x;
  for (int d = tid; d < 2048; d += 256) {
    float s = 0.f;
#pragma unroll
    for (int b = 0; b < B_; ++b) s += mv[b * L_ + d];
    av[d] = s;
  }
  __syncthreads();
  for (int kk = 0; kk < K_; ++kk) {
    float bv = -INFINITY; int bi = 0;
    for (int d = tid; d < 2048; d += 256) {
      float vv = av[d];
      if (vv > bv) { bv = vv; bi = d; }
    }
    rv[tid] = bv; ri[tid] = bi;
    __syncthreads();
    for (int off = 128; off > 0; off >>= 1) {
      if (tid < off) {
        float v2 = rv[tid + off]; int i2 = ri[tid + off];
        if (v2 > rv[tid] || (v2 == rv[tid] && i2 < ri[tid])) { rv[tid] = v2; ri[tid] = i2; }
      }
      __syncthreads();
    }
    if (tid == 0) { sidx[kk] = ri[0]; av[ri[0]] = -INFINITY; }
    __syncthreads();
  }
  if (tid < K_) topk[tid] = sidx[tid];
  if (tid < B_) {
    float xk[K_], m = -INFINITY;
#pragma unroll
    for (int kk = 0; kk < K_; ++kk) { xk[kk] = mv[tid * L_ + sidx[kk]]; m = fmaxf(m, xk[kk]); }
    float s = 0.f;
#pragma unroll
    for (int kk = 0; kk < K_; ++kk) { xk[kk] = expf(xk[kk] - m); s += xk[kk]; }
#pragma unroll
    for (int kk = 0; kk < K_; ++kk) wts[tid * K_ + kk] = xk[kk] / s;
  }
}

// ---------- kernel G: out[b,t,h,e] = sum_k w[b,k] * v[b,(t+d_k)%L,h,e] ----------
__global__ __launch_bounds__(256) void aggregate_kernel(
    const float4* __restrict__ v4, const int* __restrict__ topk,
    const float* __restrict__ wts, float4* __restrict__ out4) {
  __shared__ int   sidx[K_];
  __shared__ float sw[B_][K_];
  int tid = threadIdx.x;
  if (tid < K_) sidx[tid] = topk[tid];
  if (tid < B_ * K_) sw[tid / K_][tid % K_] = wts[tid];
  __syncthreads();
  int idx = blockIdx.x * 256 + tid;
  int c4  = idx & 127;
  int row = idx >> 7;
  int t   = row & (L_ - 1);
  int b   = row >> 11;
  float4 acc = make_float4(0.f, 0.f, 0.f, 0.f);
#pragma unroll
  for (int kk = 0; kk < K_; ++kk) {
    int s = t + sidx[kk];
    if (s >= L_) s -= L_;
    float w = sw[b][kk];
    float4 val = v4[((size_t)(b * L_ + s) << 7) + c4];
    acc.x += w * val.x; acc.y += w * val.y;
    acc.z += w * val.z; acc.w += w * val.w;
  }
  out4[idx] = acc;
}

extern "C" void kernel_launch(void* const* d_in, const int* in_sizes, int n_in,
                              void* d_out, int out_size, void* d_ws, size_t ws_size,
                              hipStream_t stream) {
  const float* q = (const float*)d_in[0];
  const float* k = (const float*)d_in[1];
  const float* v = (const float*)d_in[2];
  float* out = (float*)d_out;

  char* ws = (char*)d_ws;
  float2* part = (float2*)(ws + PART_OFF);
  float2* Sg   = (float2*)(ws + SG_OFF);
  float*  mv   = (float*) (ws + MV_OFF);
  int*    topk = (int*)   (ws + TK_OFF);
  float*  wts  = (float*) (ws + W_OFF);

  fft_corr_kernel<<<NCH / 4, 256, 4 * 2112 * sizeof(float2), stream>>>(q, k, part);
  reduce_R_kernel<<<(B_ * 8 * L_) / 256, 256, 0, stream>>>(part, Sg);
  ifft_kernel<<<B_, 256, 0, stream>>>(Sg, mv);
  topk_kernel<<<1, 256, 0, stream>>>(mv, topk, wts);
  aggregate_kernel<<<(B_ * L_ * C_ / 4) / 256, 256, 0, stream>>>(
      (const float4*)v, topk, wts, (float4*)out);
}